// Round 14
// baseline (2164.703 us; speedup 1.0000x reference)
//
#include <hip/hip_runtime.h>
#include <math.h>

#define T_LEN 8000
#define BATCH 2
#define CCH 512
#define SKP 256
#define AUXP 32
#define NQ 256
#define NLAYER 30
#define PADF 512
#define TPAD 8192
#define ROWS (PADF + TPAD)         // 8704 padded rows
#define HROWS TPAD                 // 8192 rows (z, h, y1)

typedef unsigned short hfu;        // fp16 as raw bits
typedef unsigned int u32;
typedef __attribute__((ext_vector_type(8))) _Float16 half8;
typedef __attribute__((ext_vector_type(4))) float f32x4;

#define GLOAD16(g, l)                                                          \
  __builtin_amdgcn_global_load_lds(                                            \
      (const __attribute__((address_space(1))) void*)(g),                      \
      (__attribute__((address_space(3))) void*)(l), 16, 0, 0)

__device__ inline hfu hfbits(float f) {
  union { _Float16 h; hfu u; } x;
  x.h = (_Float16)f;
  return x.u;
}
__device__ inline u32 pk2(float a, float b) {
  return (u32)hfbits(a) | ((u32)hfbits(b) << 16);
}
__device__ inline uint4 pk8(const float f[8]) {
  return make_uint4(pk2(f[0], f[1]), pk2(f[2], f[3]), pk2(f[4], f[5]), pk2(f[6], f[7]));
}
// pair-interleaved XOR LDS layout for BK=32 tiles (4 chunks of 16B per row).
// slot s -> pr=s>>3, w=s&7, row=2*pr+(w&1), ck=(w>>1)^(pr&3). Reads 2-way (free).
__device__ inline int ldsL(int row, int ck) {
  return ((row >> 1) << 3) + ((((ck) ^ ((row >> 1) & 3)) << 1) | (row & 1));
}

// ---------------- utility: zero / converts ----------------
__global__ __launch_bounds__(256) void zero16(uint4* p, int n) {
  for (int i = blockIdx.x * 256 + threadIdx.x; i < n; i += gridDim.x * 256)
    p[i] = make_uint4(0u, 0u, 0u, 0u);
}

// dil weights: [30][512][512][2] f32 -> [30][2][512][512] fp16.
__global__ __launch_bounds__(256) void cvt_dil2b(const float* __restrict__ inS,
                                                 const float* __restrict__ inT,
                                                 hfu* __restrict__ outS, hfu* __restrict__ outT) {
  const long NG = (long)NLAYER * CCH * (CCH / 8);
  for (long g2 = (long)blockIdx.x * 256 + threadIdx.x; g2 < 2 * NG; g2 += (long)gridDim.x * 256) {
    const int sel = (int)(g2 >= NG);
    const long g = sel ? (g2 - NG) : g2;
    const float* in = sel ? inT : inS;
    hfu* out = sel ? outT : outS;
    const int i8 = (int)(g & 63) * 8;
    const int o = (int)((g >> 6) & 511);
    const int l = (int)(g >> 15);
    const float* pp = in + (((size_t)l * CCH + o) * CCH + i8) * 2;
    float4 a = *(const float4*)pp;
    float4 bq = *(const float4*)(pp + 4);
    float4 c = *(const float4*)(pp + 8);
    float4 e = *(const float4*)(pp + 12);
    const float t0[8] = {a.x, a.z, bq.x, bq.z, c.x, c.z, e.x, e.z};
    const float t1[8] = {a.y, a.w, bq.y, bq.w, c.y, c.w, e.y, e.w};
    hfu* ob = out + ((size_t)l * 2 * CCH + o) * CCH + i8;
    *(uint4*)ob = pk8(t0);
    *(uint4*)(ob + (size_t)CCH * CCH) = pk8(t1);
  }
}

// skip_w [30][256][512] + res_w [30][512][512] -> stacked [30][768][512] fp16
__global__ __launch_bounds__(256) void cvt_skipres(const float* __restrict__ skw,
                                                   const float* __restrict__ rsw,
                                                   hfu* __restrict__ out) {
  const long NG = (long)NLAYER * 768 * (CCH / 4);
  for (long g = (long)blockIdx.x * 256 + threadIdx.x; g < NG; g += (long)gridDim.x * 256) {
    const int i4 = (int)(g & 127) * 4;
    const int r = (int)((g >> 7) % 768);
    const int l = (int)(g / (128 * 768));
    const float* src = (r < SKP) ? (skw + ((size_t)l * SKP + r) * CCH + i4)
                                 : (rsw + ((size_t)l * CCH + (r - SKP)) * CCH + i4);
    float4 f = *(const float4*)src;
    *(uint2*)(out + ((size_t)l * 768 + r) * CCH + i4) = make_uint2(pk2(f.x, f.y), pk2(f.z, f.w));
  }
}

// aux weights [30][512][28] -> [30][512][32] fp16 zero-padded
__global__ __launch_bounds__(256) void cvt_aux(const float* __restrict__ in, hfu* __restrict__ out) {
  const int N = NLAYER * CCH * AUXP;
  for (int i = blockIdx.x * 256 + threadIdx.x; i < N; i += gridDim.x * 256) {
    const int j = i & 31;
    const int o = (i >> 5) & 511;
    const int l = i >> 14;
    float v = (j < 28) ? in[((size_t)l * CCH + o) * 28 + j] : 0.f;
    out[i] = hfbits(v);
  }
}

__global__ __launch_bounds__(256) void cvt_copy(const float* __restrict__ in, hfu* __restrict__ out, int n) {
  for (int i = blockIdx.x * 256 + threadIdx.x; i < n; i += gridDim.x * 256)
    out[i] = hfbits(in[i]);
}

// causal_w [512][256][2] f32 -> cwt [2][256][512] f32
__global__ __launch_bounds__(256) void cvt_cwt(const float* __restrict__ cw, float* __restrict__ out) {
  const int N = 2 * NQ * CCH;
  for (int i = blockIdx.x * 256 + threadIdx.x; i < N; i += gridDim.x * 256) {
    const int tap = i >> 17;
    const int r = i & 131071;
    const int xq = r >> 9;
    const int o = r & 511;
    out[i] = cw[((size_t)o * NQ + xq) * 2 + tap];
  }
}

// h [b][28][8000] f32 -> [b][8192][32] fp16 zero-padded
__global__ __launch_bounds__(256) void htrans_kernel(const float* __restrict__ h, hfu* __restrict__ hbf) {
  const int b = blockIdx.y;
  const int t = blockIdx.x * 64 + (threadIdx.x & 63);
  const int j0 = threadIdx.x >> 6;
#pragma unroll
  for (int j = j0; j < AUXP; j += 4) {
    float v = (j < 28 && t < T_LEN) ? h[((size_t)b * 28 + j) * T_LEN + t] : 0.f;
    hbf[((size_t)b * HROWS + t) * AUXP + j] = hfbits(v);
  }
}

// ---------------- embed (coalesced via cwt) ----------------
template <int PRE>
__global__ __launch_bounds__(256) void embed_kernel(const int* __restrict__ x,
                                                    const float* __restrict__ cwt,
                                                    const float* __restrict__ cb,
                                                    float* __restrict__ outf,
                                                    hfu* __restrict__ outb) {
  const int b = blockIdx.y;
  const int t = blockIdx.x * 4 + (threadIdx.x >> 6);
  const int o = (threadIdx.x & 63) * 8;
  const int xc = x[(size_t)b * T_LEN + t] & 255;
  const int xp = (t > 0) ? (x[(size_t)b * T_LEN + t - 1] & 255) : 0;
  const float won = (t > 0) ? 1.f : 0.f;
  const float* c1 = cwt + 131072 + (size_t)xc * CCH + o;
  const float* c0 = cwt + (size_t)xp * CCH + o;
  float v[8];
#pragma unroll
  for (int j = 0; j < 8; ++j) v[j] = cb[o + j] + c1[j] + won * c0[j];
  if (PRE) {
    *(uint4*)&outb[((size_t)b * ROWS + PADF + t) * CCH + o] = pk8(v);
  } else {
    float* po = outf + ((size_t)b * ROWS + PADF + t) * CCH + o;
    *(float4*)po = make_float4(v[0], v[1], v[2], v[3]);
    *(float4*)(po + 4) = make_float4(v[4], v[5], v[6], v[7]);
  }
}

// ---------------- gate: sig/tanh dilated GEMMs + aux + gating ----------------
// BM=128, BN=256, BK=32, 33 UNIFORM K-steps (32 dil + 1 aux, same geometry).
// 512 threads (8 waves: wm2 x wn4, wave tile 64x64, acc 128 VGPR).
// Grid 256 = 1 block/CU. 3-phase LDS ring (96KB dynamic), DEPTH-2 prefetch:
// per step [vmcnt(8); barrier; ds_read+MFMA; barrier; stage(ih+3)] — each
// step's 4 loads covered by ~2 full compute steps, never drained mid-loop.
template <int PRE>
__global__ __launch_bounds__(512, 2) void gate_kernel(
    const hfu* __restrict__ actb, const float* __restrict__ actf,
    const hfu* __restrict__ hbf,
    const void* __restrict__ wsp, const void* __restrict__ wtp,
    const hfu* __restrict__ auxs, const hfu* __restrict__ auxt,
    const float* __restrict__ bs1, const float* __restrict__ bs2,
    const float* __restrict__ bt1, const float* __restrict__ bt2,
    hfu* __restrict__ z, int d) {
  extern __shared__ uint4 smd[];  // 3 phases x {As 512, At 512, B 1024} uint4
  const int tid = threadIdx.x;
  const int lane = tid & 63, wid = tid >> 6;
  const int wm = wid >> 2, wn = wid & 3;
  const int lr = lane & 15, lq = lane >> 4;

  const int n = blockIdx.x;               // 256 = 8 xcd * 32
  const int f = (n & 7) * 32 + (n >> 3);
  const int tt = f >> 3, inner = f & 7;   // 32 t-tiles x (4 og x 2 b)
  const int o0 = (inner >> 1) * 128;
  const int b = inner & 1;
  const int t0 = tt * 256;

  // staging decode: thread owns slots {tid (A/At + B rows 0..127), 512+tid (B rows 128..255)}
  const int row = 2 * (tid >> 3) + (tid & 1);              // 0..127
  const int ck = ((tid & 7) >> 1) ^ ((tid >> 3) & 3);      // 0..3

  f32x4 accS[4][4] = {};
  f32x4 accT[4][4] = {};

  if (PRE) {
    const hfu* wsPtr = (const hfu*)wsp + ((size_t)CCH + o0 + row) * CCH + ck * 8;  // tau=1
    const hfu* wtPtr = (const hfu*)wtp + ((size_t)CCH + o0 + row) * CCH + ck * 8;
    const hfu* bP0 = actb + ((size_t)b * ROWS + PADF + t0 + row) * CCH + ck * 8;
    const hfu* bP1 = bP0 + (size_t)128 * CCH;
    int offA[4], offB[4];
#pragma unroll
    for (int mr = 0; mr < 4; ++mr) offA[mr] = ldsL(wm * 64 + mr * 16 + lr, lq);
#pragma unroll
    for (int nr = 0; nr < 4; ++nr) offB[nr] = ldsL(wn * 64 + nr * 16 + lr, lq);

    auto stage = [&](int ihs) {
      uint4* dst = smd + (ihs % 3) * 2048;
      if (ihs < 32) {
        GLOAD16(wsPtr, &dst[tid]);
        GLOAD16(wtPtr, &dst[512 + tid]);
        GLOAD16(bP0, &dst[1024 + tid]);
        GLOAD16(bP1, &dst[1536 + tid]);
        if (ihs == 15) {  // flip tau=1(koff=480) -> tau=0(koff=0)
          wsPtr -= (size_t)CCH * CCH + 480;
          wtPtr -= (size_t)CCH * CCH + 480;
          bP0 -= 480 + (size_t)d * CCH;
          bP1 -= 480 + (size_t)d * CCH;
        } else {
          wsPtr += 32; wtPtr += 32; bP0 += 32; bP1 += 32;
        }
      } else {  // aux step: identical K=32 geometry
        GLOAD16(auxs + (size_t)(o0 + row) * AUXP + ck * 8, &dst[tid]);
        GLOAD16(auxt + (size_t)(o0 + row) * AUXP + ck * 8, &dst[512 + tid]);
        GLOAD16(hbf + ((size_t)b * HROWS + t0 + row) * AUXP + ck * 8, &dst[1024 + tid]);
        GLOAD16(hbf + ((size_t)b * HROWS + t0 + 128 + row) * AUXP + ck * 8, &dst[1536 + tid]);
      }
    };

    stage(0); stage(1); stage(2);           // depth-2 prologue (12 loads in flight)
    for (int ih = 0; ih < 33; ++ih) {
      if (ih <= 30)
        asm volatile("s_waitcnt vmcnt(8)" ::: "memory");   // step-ih landed; 8 newer fly
      else if (ih == 31)
        asm volatile("s_waitcnt vmcnt(4)" ::: "memory");
      else
        asm volatile("s_waitcnt vmcnt(0)" ::: "memory");
      __builtin_amdgcn_s_barrier();
      __builtin_amdgcn_sched_barrier(0);
      const uint4* base = smd + (ih % 3) * 2048;
      half8 af[4], ag[4], bv[4];
#pragma unroll
      for (int mr = 0; mr < 4; ++mr) {
        af[mr] = *(const half8*)&base[offA[mr]];
        ag[mr] = *(const half8*)&base[512 + offA[mr]];
      }
#pragma unroll
      for (int nr = 0; nr < 4; ++nr) bv[nr] = *(const half8*)&base[1024 + offB[nr]];
      __builtin_amdgcn_s_setprio(1);
#pragma unroll
      for (int mr = 0; mr < 4; ++mr)
#pragma unroll
        for (int nr = 0; nr < 4; ++nr) {
          accS[mr][nr] = __builtin_amdgcn_mfma_f32_16x16x32_f16(af[mr], bv[nr], accS[mr][nr], 0, 0, 0);
          accT[mr][nr] = __builtin_amdgcn_mfma_f32_16x16x32_f16(ag[mr], bv[nr], accT[mr][nr], 0, 0, 0);
        }
      __builtin_amdgcn_s_setprio(0);
      __builtin_amdgcn_sched_barrier(0);
      __builtin_amdgcn_s_barrier();          // all waves done reading phase ih%3
      if (ih <= 29) stage(ih + 3);           // overwrite just-consumed phase
    }
  } else {
    // fp32-source fallback (correctness only): 3-phase, __syncthreads
    for (int ih = 0; ih < 33; ++ih) {
      uint4* dst = smd + (ih % 3) * 2048;
      if (ih < 32) {
        const int tau = (ih < 16) ? 1 : 0;
        const int koff = (ih & 15) * 32;
        const float* wsf = (const float*)wsp;
        const float* wtf = (const float*)wtp;
        const size_t fb = ((size_t)(o0 + row) * CCH + koff + ck * 8) * 2;
        float vs[8], vt[8];
#pragma unroll
        for (int j = 0; j < 4; ++j) {
          float4 fs = *(const float4*)&wsf[fb + j * 4];
          float4 ft = *(const float4*)&wtf[fb + j * 4];
          vs[2 * j] = tau ? fs.y : fs.x;
          vs[2 * j + 1] = tau ? fs.w : fs.z;
          vt[2 * j] = tau ? ft.y : ft.x;
          vt[2 * j + 1] = tau ? ft.w : ft.z;
        }
        dst[tid] = pk8(vs);
        dst[512 + tid] = pk8(vt);
#pragma unroll
        for (int c = 0; c < 2; ++c) {
          const int rr = row + c * 128;
          const float* ar = actf + ((size_t)b * ROWS + PADF + t0 + rr - (tau ? 0 : d)) * CCH + koff + ck * 8;
          float4 f0 = *(const float4*)&ar[0];
          float4 f1 = *(const float4*)&ar[4];
          float vb[8] = {f0.x, f0.y, f0.z, f0.w, f1.x, f1.y, f1.z, f1.w};
          dst[1024 + c * 512 + tid] = pk8(vb);
        }
      } else {
        dst[tid] = *(const uint4*)&auxs[(size_t)(o0 + row) * AUXP + ck * 8];
        dst[512 + tid] = *(const uint4*)&auxt[(size_t)(o0 + row) * AUXP + ck * 8];
        dst[1024 + tid] = *(const uint4*)&hbf[((size_t)b * HROWS + t0 + row) * AUXP + ck * 8];
        dst[1536 + tid] = *(const uint4*)&hbf[((size_t)b * HROWS + t0 + 128 + row) * AUXP + ck * 8];
      }
      __syncthreads();
      const uint4* base = smd + (ih % 3) * 2048;
      half8 af[4], ag[4], bv[4];
#pragma unroll
      for (int mr = 0; mr < 4; ++mr) {
        const int idx = ldsL(wm * 64 + mr * 16 + lr, lq);
        af[mr] = *(const half8*)&base[idx];
        ag[mr] = *(const half8*)&base[512 + idx];
      }
#pragma unroll
      for (int nr = 0; nr < 4; ++nr)
        bv[nr] = *(const half8*)&base[1024 + ldsL(wn * 64 + nr * 16 + lr, lq)];
#pragma unroll
      for (int mr = 0; mr < 4; ++mr)
#pragma unroll
        for (int nr = 0; nr < 4; ++nr) {
          accS[mr][nr] = __builtin_amdgcn_mfma_f32_16x16x32_f16(af[mr], bv[nr], accS[mr][nr], 0, 0, 0);
          accT[mr][nr] = __builtin_amdgcn_mfma_f32_16x16x32_f16(ag[mr], bv[nr], accT[mr][nr], 0, 0, 0);
        }
      __syncthreads();
    }
  }

  // epilogue: bias + sigmoid*tanh -> z fp16 [b][t][ch]
#pragma unroll
  for (int mr = 0; mr < 4; ++mr) {
    const int ob = o0 + wm * 64 + mr * 16 + lq * 4;
    float4 x1 = *(const float4*)&bs1[ob];
    float4 x2 = *(const float4*)&bs2[ob];
    float4 y1 = *(const float4*)&bt1[ob];
    float4 y2 = *(const float4*)&bt2[ob];
    const float sb[4] = {x1.x + x2.x, x1.y + x2.y, x1.z + x2.z, x1.w + x2.w};
    const float tb[4] = {y1.x + y2.x, y1.y + y2.y, y1.z + y2.z, y1.w + y2.w};
#pragma unroll
    for (int nr = 0; nr < 4; ++nr) {
      const int t = t0 + wn * 64 + nr * 16 + lr;
      float zv[4];
#pragma unroll
      for (int j = 0; j < 4; ++j) {
        float sv = accS[mr][nr][j] + sb[j];
        float tv = accT[mr][nr][j] + tb[j];
        float sg = __builtin_amdgcn_rcpf(1.f + __expf(-sv));
        float e2 = __expf(2.f * tv);
        float th = 1.f - 2.f * __builtin_amdgcn_rcpf(e2 + 1.f);
        zv[j] = sg * th;
      }
      *(uint2*)&z[((size_t)b * HROWS + t) * CCH + ob] = make_uint2(pk2(zv[0], zv[1]), pk2(zv[2], zv[3]));
    }
  }
}

// ---------------- update: [skip_w; res_w] @ z, RMW skip/residual ----------------
// BM=128, BN=128, BK=32, 512 threads, grid 768 (xcd owns tt [xcd*8,...)).
// 3-phase LDS ring (48KB), DEPTH-2 prefetch, vmcnt(4)/(2)/(0).
template <int PRE>
__global__ __launch_bounds__(512, 4) void update_kernel(
    const hfu* __restrict__ z, const void* __restrict__ wp,
    const float* __restrict__ skwf, const float* __restrict__ rswf,
    const float* __restrict__ skb, const float* __restrict__ rsb,
    float* __restrict__ skip, hfu* __restrict__ skiph,
    float* __restrict__ outf, hfu* __restrict__ outb) {
  __shared__ uint4 sm[3072];  // 3 phases x {A 512, B 512}
  const int tid = threadIdx.x;
  const int lane = tid & 63, wid = tid >> 6;
  const int wm = wid >> 1, wn = wid & 1;
  const int lr = lane & 15, lq = lane >> 4;

  const int n = blockIdx.x;                // 768 = 8 xcd * 96
  const int xcd = n & 7, j = n >> 3;       // j 0..95
  const int ttl = j / 12, inner = j % 12;  // 8 local t-tiles x (6 rg x 2 b)
  const int tt = xcd * 8 + ttl;
  if (tt > 62) return;                     // 63 t-tiles; xcd7 idles 12 blocks
  const int rg = inner >> 1, b = inner & 1;
  const int r0 = rg * 128;                 // 0..640
  const int t0 = tt * 128;

  f32x4 acc[2][4] = {};
  const int row = 2 * (tid >> 3) + (tid & 1);           // 0..127
  const int ck = ((tid & 7) >> 1) ^ ((tid >> 3) & 3);

  if (PRE) {
    const hfu* wPtr = (const hfu*)wp + (size_t)(r0 + row) * CCH + ck * 8;
    const hfu* zPtr = z + ((size_t)b * HROWS + t0 + row) * CCH + ck * 8;
    int offa[2], offb[4];
#pragma unroll
    for (int mr = 0; mr < 2; ++mr) offa[mr] = ldsL(wm * 32 + mr * 16 + lr, lq);
#pragma unroll
    for (int nr = 0; nr < 4; ++nr) offb[nr] = ldsL(wn * 64 + nr * 16 + lr, lq);

    auto stage_u = [&](int ihs) {
      uint4* dst = sm + (ihs % 3) * 1024;
      GLOAD16(wPtr, &dst[tid]);
      GLOAD16(zPtr, &dst[512 + tid]);
      wPtr += 32; zPtr += 32;
    };
    stage_u(0); stage_u(1); stage_u(2);
    for (int ih = 0; ih < 16; ++ih) {
      if (ih <= 13)
        asm volatile("s_waitcnt vmcnt(4)" ::: "memory");
      else if (ih == 14)
        asm volatile("s_waitcnt vmcnt(2)" ::: "memory");
      else
        asm volatile("s_waitcnt vmcnt(0)" ::: "memory");
      __builtin_amdgcn_s_barrier();
      __builtin_amdgcn_sched_barrier(0);
      const uint4* base = sm + (ih % 3) * 1024;
      half8 av[2], bv[4];
#pragma unroll
      for (int mr = 0; mr < 2; ++mr) av[mr] = *(const half8*)&base[offa[mr]];
#pragma unroll
      for (int nr = 0; nr < 4; ++nr) bv[nr] = *(const half8*)&base[512 + offb[nr]];
      __builtin_amdgcn_s_setprio(1);
#pragma unroll
      for (int mr = 0; mr < 2; ++mr)
#pragma unroll
        for (int nr = 0; nr < 4; ++nr)
          acc[mr][nr] = __builtin_amdgcn_mfma_f32_16x16x32_f16(av[mr], bv[nr], acc[mr][nr], 0, 0, 0);
      __builtin_amdgcn_s_setprio(0);
      __builtin_amdgcn_sched_barrier(0);
      __builtin_amdgcn_s_barrier();
      if (ih <= 12) stage_u(ih + 3);
    }
  } else {
    for (int ih = 0; ih < 16; ++ih) {
      uint4* dst = sm + (ih % 3) * 1024;
      const int k0 = ih * 32;
      const int R = r0 + row;
      const float* src = (R < SKP) ? (skwf + (size_t)R * CCH + k0 + ck * 8)
                                   : (rswf + (size_t)(R - SKP) * CCH + k0 + ck * 8);
      float4 f0 = *(const float4*)&src[0];
      float4 f1 = *(const float4*)&src[4];
      float v[8] = {f0.x, f0.y, f0.z, f0.w, f1.x, f1.y, f1.z, f1.w};
      dst[tid] = pk8(v);
      dst[512 + tid] = *(const uint4*)&z[((size_t)b * HROWS + t0 + row) * CCH + k0 + ck * 8];
      __syncthreads();
      const uint4* base = sm + (ih % 3) * 1024;
      half8 av[2], bv[4];
#pragma unroll
      for (int mr = 0; mr < 2; ++mr) av[mr] = *(const half8*)&base[ldsL(wm * 32 + mr * 16 + lr, lq)];
#pragma unroll
      for (int nr = 0; nr < 4; ++nr) bv[nr] = *(const half8*)&base[512 + ldsL(wn * 64 + nr * 16 + lr, lq)];
#pragma unroll
      for (int mr = 0; mr < 2; ++mr)
#pragma unroll
        for (int nr = 0; nr < 4; ++nr)
          acc[mr][nr] = __builtin_amdgcn_mfma_f32_16x16x32_f16(av[mr], bv[nr], acc[mr][nr], 0, 0, 0);
      __syncthreads();
    }
  }

  const bool iskip = (r0 < SKP);
#pragma unroll
  for (int mr = 0; mr < 2; ++mr) {
    const int R = r0 + wm * 32 + mr * 16 + lq * 4;
#pragma unroll
    for (int nr = 0; nr < 4; ++nr) {
      const int t = t0 + wn * 64 + nr * 16 + lr;
      if (t < T_LEN) {
        if (iskip) {
          float4 bb = *(const float4*)&skb[R];
          if (PRE) {
            hfu* ps = &skiph[((size_t)b * T_LEN + t) * SKP + R];
            uint2 old = *(uint2*)ps;
            const _Float16* hp = (const _Float16*)&old;
            float v0 = (float)hp[0] + acc[mr][nr][0] + bb.x;
            float v1 = (float)hp[1] + acc[mr][nr][1] + bb.y;
            float v2 = (float)hp[2] + acc[mr][nr][2] + bb.z;
            float v3 = (float)hp[3] + acc[mr][nr][3] + bb.w;
            *(uint2*)ps = make_uint2(pk2(v0, v1), pk2(v2, v3));
          } else {
            float4* p = (float4*)&skip[((size_t)b * T_LEN + t) * SKP + R];
            float4 v = *p;
            v.x += acc[mr][nr][0] + bb.x;
            v.y += acc[mr][nr][1] + bb.y;
            v.z += acc[mr][nr][2] + bb.z;
            v.w += acc[mr][nr][3] + bb.w;
            *p = v;
          }
        } else {
          const int rr = R - SKP;
          float4 bb = *(const float4*)&rsb[rr];
          if (PRE) {
            hfu* pb = &outb[((size_t)b * ROWS + PADF + t) * CCH + rr];
            uint2 old = *(uint2*)pb;
            const _Float16* hp = (const _Float16*)&old;
            float v0 = (float)hp[0] + acc[mr][nr][0] + bb.x;
            float v1 = (float)hp[1] + acc[mr][nr][1] + bb.y;
            float v2 = (float)hp[2] + acc[mr][nr][2] + bb.z;
            float v3 = (float)hp[3] + acc[mr][nr][3] + bb.w;
            *(uint2*)pb = make_uint2(pk2(v0, v1), pk2(v2, v3));
          } else {
            float4* p = (float4*)&outf[((size_t)b * ROWS + PADF + t) * CCH + rr];
            float4 v = *p;
            v.x += acc[mr][nr][0] + bb.x;
            v.y += acc[mr][nr][1] + bb.y;
            v.z += acc[mr][nr][2] + bb.z;
            v.w += acc[mr][nr][3] + bb.w;
            *p = v;
          }
        }
      }
    }
  }
}

// ---------------- post1: y1 = relu(W1 @ relu(skip) + b1) -> fp16 ----------------
template <int PRE>
__global__ __launch_bounds__(256, 2) void post1_kernel(const float* __restrict__ skip,
                                                       const hfu* __restrict__ skiph,
                                                       const hfu* __restrict__ w,
                                                       const float* __restrict__ bias,
                                                       hfu* __restrict__ y1) {
  __shared__ uint4 sm[2048];
  uint4* sA = sm;
  uint4* sB = sm + 1024;
  const int tid = threadIdx.x;
  const int lane = tid & 63, wid = tid >> 6;
  const int wm = wid >> 1, wn = wid & 1;
  const int lr = lane & 15, lq = lane >> 4;
  const int t0 = blockIdx.x * 128;
  const int r0 = blockIdx.y * 128;
  const int b = blockIdx.z;
  f32x4 acc[4][4] = {};
  for (int kt = 0; kt < 4; ++kt) {  // K=256
#pragma unroll
    for (int c = 0; c < 4; ++c) {
      const int cb = c * 256 + wid * 64;
      const int ch = cb + lane;
      const int ksub = ch >> 7, mn = ch & 127;
      const int k0 = kt * 64 + ksub * 8;
      GLOAD16(w + (size_t)(r0 + mn) * SKP + k0, &sA[cb]);
      int row = t0 + mn;
      if (row > T_LEN - 1) row = T_LEN - 1;
      if (PRE) {
        uint4 u = *(const uint4*)&skiph[((size_t)b * T_LEN + row) * SKP + k0];
        const _Float16* hp = (const _Float16*)&u;
        float v[8];
#pragma unroll
        for (int jj = 0; jj < 8; ++jj) v[jj] = fmaxf((float)hp[jj], 0.f);
        sB[ch] = pk8(v);
      } else {
        const float* src = skip + ((size_t)b * T_LEN + row) * SKP + k0;
        float4 f0 = *(const float4*)&src[0];
        float4 f1 = *(const float4*)&src[4];
        float v[8] = {fmaxf(f0.x, 0.f), fmaxf(f0.y, 0.f), fmaxf(f0.z, 0.f), fmaxf(f0.w, 0.f),
                      fmaxf(f1.x, 0.f), fmaxf(f1.y, 0.f), fmaxf(f1.z, 0.f), fmaxf(f1.w, 0.f)};
        sB[ch] = pk8(v);
      }
    }
    __syncthreads();
#pragma unroll
    for (int ks = 0; ks < 2; ++ks) {
      const int kb = (ks * 4 + lq) * 128;
      half8 av[4], bv[4];
#pragma unroll
      for (int r = 0; r < 4; ++r) {
        av[r] = *(const half8*)&sA[kb + wm * 64 + r * 16 + lr];
        bv[r] = *(const half8*)&sB[kb + wn * 64 + r * 16 + lr];
      }
#pragma unroll
      for (int mr = 0; mr < 4; ++mr)
#pragma unroll
        for (int nr = 0; nr < 4; ++nr)
          acc[mr][nr] = __builtin_amdgcn_mfma_f32_16x16x32_f16(av[mr], bv[nr], acc[mr][nr], 0, 0, 0);
    }
    __syncthreads();
  }
#pragma unroll
  for (int mr = 0; mr < 4; ++mr) {
    const int ob = r0 + wm * 64 + mr * 16 + lq * 4;
    float4 bb = *(const float4*)&bias[ob];
    const float bs[4] = {bb.x, bb.y, bb.z, bb.w};
#pragma unroll
    for (int nr = 0; nr < 4; ++nr) {
      const int t = t0 + wn * 64 + nr * 16 + lr;
      float v[4];
#pragma unroll
      for (int jj = 0; jj < 4; ++jj) v[jj] = fmaxf(acc[mr][nr][jj] + bs[jj], 0.f);
      *(uint2*)&y1[((size_t)b * HROWS + t) * SKP + ob] = make_uint2(pk2(v[0], v[1]), pk2(v[2], v[3]));
    }
  }
}

// ---------------- post2: out = W2 @ y1 + b2 -> d_out [b][t][q] fp32 ----------------
__global__ __launch_bounds__(256, 2) void post2_kernel(const hfu* __restrict__ y1,
                                                       const hfu* __restrict__ w,
                                                       const float* __restrict__ bias,
                                                       float* __restrict__ outp) {
  __shared__ uint4 sm[2048];
  uint4* sA = sm;
  uint4* sB = sm + 1024;
  const int tid = threadIdx.x;
  const int lane = tid & 63, wid = tid >> 6;
  const int wm = wid >> 1, wn = wid & 1;
  const int lr = lane & 15, lq = lane >> 4;
  const int t0 = blockIdx.x * 128;
  const int r0 = blockIdx.y * 128;
  const int b = blockIdx.z;
  f32x4 acc[4][4] = {};
  for (int kt = 0; kt < 4; ++kt) {
#pragma unroll
    for (int c = 0; c < 4; ++c) {
      const int cb = c * 256 + wid * 64;
      const int ch = cb + lane;
      const int ksub = ch >> 7, mn = ch & 127;
      const int k0 = kt * 64 + ksub * 8;
      GLOAD16(w + (size_t)(r0 + mn) * SKP + k0, &sA[cb]);
      GLOAD16(y1 + ((size_t)b * HROWS + t0 + mn) * SKP + k0, &sB[cb]);
    }
    __syncthreads();
#pragma unroll
    for (int ks = 0; ks < 2; ++ks) {
      const int kb = (ks * 4 + lq) * 128;
      half8 av[4], bv[4];
#pragma unroll
      for (int r = 0; r < 4; ++r) {
        av[r] = *(const half8*)&sA[kb + wm * 64 + r * 16 + lr];
        bv[r] = *(const half8*)&sB[kb + wn * 64 + r * 16 + lr];
      }
#pragma unroll
      for (int mr = 0; mr < 4; ++mr)
#pragma unroll
        for (int nr = 0; nr < 4; ++nr)
          acc[mr][nr] = __builtin_amdgcn_mfma_f32_16x16x32_f16(av[mr], bv[nr], acc[mr][nr], 0, 0, 0);
    }
    __syncthreads();
  }
#pragma unroll
  for (int mr = 0; mr < 4; ++mr) {
    const int ob = r0 + wm * 64 + mr * 16 + lq * 4;
    float4 bb = *(const float4*)&bias[ob];
#pragma unroll
    for (int nr = 0; nr < 4; ++nr) {
      const int t = t0 + wn * 64 + nr * 16 + lr;
      if (t < T_LEN) {
        float4 v;
        v.x = acc[mr][nr][0] + bb.x;
        v.y = acc[mr][nr][1] + bb.y;
        v.z = acc[mr][nr][2] + bb.z;
        v.w = acc[mr][nr][3] + bb.w;
        *(float4*)&outp[((size_t)b * T_LEN + t) * NQ + ob] = v;
      }
    }
  }
}

extern "C" void kernel_launch(void* const* d_in, const int* in_sizes, int n_in,
                              void* d_out, int out_size, void* d_ws, size_t ws_size,
                              hipStream_t stream) {
  const int* x = (const int*)d_in[0];
  const float* h = (const float*)d_in[1];
  const float* causal_w = (const float*)d_in[2];
  const float* causal_b = (const float*)d_in[3];
  const float* dil_sig_w = (const float*)d_in[4];
  const float* dil_sig_b = (const float*)d_in[5];
  const float* dil_tanh_w = (const float*)d_in[6];
  const float* dil_tanh_b = (const float*)d_in[7];
  const float* aux_sig_w = (const float*)d_in[8];
  const float* aux_sig_b = (const float*)d_in[9];
  const float* aux_tanh_w = (const float*)d_in[10];
  const float* aux_tanh_b = (const float*)d_in[11];
  const float* skip_w = (const float*)d_in[12];
  const float* skip_b = (const float*)d_in[13];
  const float* res_w = (const float*)d_in[14];
  const float* res_b = (const float*)d_in[15];
  const float* post1_w = (const float*)d_in[16];
  const float* post1_b = (const float*)d_in[17];
  const float* post2_w = (const float*)d_in[18];
  const float* post2_b = (const float*)d_in[19];
  float* outp = (float*)d_out;

  hipFuncSetAttribute((const void*)gate_kernel<1>,
                      hipFuncAttributeMaxDynamicSharedMemorySize, 98304);
  hipFuncSetAttribute((const void*)gate_kernel<0>,
                      hipFuncAttributeMaxDynamicSharedMemorySize, 98304);

  char* p = (char*)d_ws;
  auto alloc = [&](size_t bytes) {
    char* r = p;
    p += (bytes + 255) & ~(size_t)255;
    return r;
  };
  float* outf = (float*)alloc((size_t)BATCH * ROWS * CCH * 4);   // fp32 residual (PRE=0)
  float* skip = (float*)alloc((size_t)BATCH * T_LEN * SKP * 4);  // fp32 skip (PRE=0)
  hfu* zb = (hfu*)alloc((size_t)BATCH * HROWS * CCH * 2);        // z fp16 (reused as y1)
  hfu* hbf = (hfu*)alloc((size_t)BATCH * HROWS * AUXP * 2);
  hfu* auxsb = (hfu*)alloc((size_t)NLAYER * CCH * AUXP * 2);
  hfu* auxtb = (hfu*)alloc((size_t)NLAYER * CCH * AUXP * 2);
  hfu* p1b = (hfu*)alloc((size_t)NQ * SKP * 2);
  hfu* p2b = (hfu*)alloc((size_t)NQ * SKP * 2);
  float* cwt = (float*)alloc((size_t)2 * NQ * CCH * 4);          // transposed causal_w
  hfu* skiph = (hfu*)alloc((size_t)BATCH * T_LEN * SKP * 2);     // fp16 skip (PRE)
  hfu* y1 = zb;
  // optional (PRE) region
  hfu* outb = (hfu*)alloc((size_t)BATCH * ROWS * CCH * 2);       // fp16 residual (PRE)
  hfu* dilS = (hfu*)alloc((size_t)NLAYER * 2 * CCH * CCH * 2);
  hfu* dilT = (hfu*)alloc((size_t)NLAYER * 2 * CCH * CCH * 2);
  hfu* wsr = (hfu*)alloc((size_t)NLAYER * 768 * CCH * 2);
  const bool pre = ((size_t)(p - (char*)d_ws) <= ws_size);

  // weight conversions
  cvt_aux<<<256, 256, 0, stream>>>(aux_sig_w, auxsb);
  cvt_aux<<<256, 256, 0, stream>>>(aux_tanh_w, auxtb);
  cvt_copy<<<64, 256, 0, stream>>>(post1_w, p1b, NQ * SKP);
  cvt_copy<<<64, 256, 0, stream>>>(post2_w, p2b, NQ * SKP);
  cvt_cwt<<<1024, 256, 0, stream>>>(causal_w, cwt);
  if (pre) {
    cvt_dil2b<<<2048, 256, 0, stream>>>(dil_sig_w, dil_tanh_w, dilS, dilT);
    cvt_skipres<<<2048, 256, 0, stream>>>(skip_w, res_w, wsr);
  }

  // zero: skip + padded rows of the residual master in use
  if (pre) {
    zero16<<<512, 256, 0, stream>>>((uint4*)skiph, (int)((size_t)BATCH * T_LEN * SKP * 2 / 16));
    for (int b = 0; b < BATCH; ++b) {
      zero16<<<32, 256, 0, stream>>>((uint4*)(outb + (size_t)b * ROWS * CCH), PADF * CCH * 2 / 16);
      zero16<<<48, 256, 0, stream>>>((uint4*)(outb + ((size_t)b * ROWS + PADF + T_LEN) * CCH),
                                     (TPAD - T_LEN) * CCH * 2 / 16);
    }
  } else {
    zero16<<<512, 256, 0, stream>>>((uint4*)skip, (int)((size_t)BATCH * T_LEN * SKP * 4 / 16));
    for (int b = 0; b < BATCH; ++b) {
      zero16<<<64, 256, 0, stream>>>((uint4*)(outf + (size_t)b * ROWS * CCH), PADF * CCH * 4 / 16);
      zero16<<<96, 256, 0, stream>>>((uint4*)(outf + ((size_t)b * ROWS + PADF + T_LEN) * CCH),
                                     (TPAD - T_LEN) * CCH * 4 / 16);
    }
  }

  htrans_kernel<<<dim3(128, 2), 256, 0, stream>>>(h, hbf);
  if (pre)
    embed_kernel<1><<<dim3(2000, 2), 256, 0, stream>>>(x, cwt, causal_b, nullptr, outb);
  else
    embed_kernel<0><<<dim3(2000, 2), 256, 0, stream>>>(x, cwt, causal_b, outf, nullptr);

  for (int l = 0; l < NLAYER; ++l) {
    const int d = 1 << (l % 10);
    if (pre) {
      gate_kernel<1><<<256, 512, 98304, stream>>>(
          outb, nullptr, hbf, dilS + (size_t)l * 2 * CCH * CCH, dilT + (size_t)l * 2 * CCH * CCH,
          auxsb + (size_t)l * CCH * AUXP, auxtb + (size_t)l * CCH * AUXP,
          dil_sig_b + (size_t)l * CCH, aux_sig_b + (size_t)l * CCH,
          dil_tanh_b + (size_t)l * CCH, aux_tanh_b + (size_t)l * CCH, zb, d);
      update_kernel<1><<<768, 512, 0, stream>>>(
          zb, wsr + (size_t)l * 768 * CCH, nullptr, nullptr,
          skip_b + (size_t)l * SKP, res_b + (size_t)l * CCH, nullptr, skiph, nullptr, outb);
    } else {
      gate_kernel<0><<<256, 512, 98304, stream>>>(
          nullptr, outf, hbf, dil_sig_w + (size_t)l * CCH * CCH * 2,
          dil_tanh_w + (size_t)l * CCH * CCH * 2,
          auxsb + (size_t)l * CCH * AUXP, auxtb + (size_t)l * CCH * AUXP,
          dil_sig_b + (size_t)l * CCH, aux_sig_b + (size_t)l * CCH,
          dil_tanh_b + (size_t)l * CCH, aux_tanh_b + (size_t)l * CCH, zb, d);
      update_kernel<0><<<768, 512, 0, stream>>>(
          zb, nullptr, skip_w + (size_t)l * SKP * CCH, res_w + (size_t)l * CCH * CCH,
          skip_b + (size_t)l * SKP, res_b + (size_t)l * CCH, skip, nullptr, outf, nullptr);
    }
  }

  if (pre)
    post1_kernel<1><<<dim3(63, 2, BATCH), 256, 0, stream>>>(nullptr, skiph, p1b, post1_b, y1);
  else
    post1_kernel<0><<<dim3(63, 2, BATCH), 256, 0, stream>>>(skip, nullptr, p1b, post1_b, y1);
  post2_kernel<<<dim3(63, 2, BATCH), 256, 0, stream>>>(y1, p2b, post2_b, outp);
}